// Round 6
// baseline (97.569 us; speedup 1.0000x reference)
//
#include <hip/hip_runtime.h>
#include <math.h>

#define NUM_CLASSES 80
#define M_GT 128
#define QBLK 128   // anchors per block; 2 threads per anchor (GT halves)

// ws layout: [0,24): double acc[3] = {box_l, cls_l, npos}
__global__ void yolo_init_acc(double* acc) {
    if (threadIdx.x < 3) acc[threadIdx.x] = 0.0;
}

__device__ __forceinline__ float focal_neg(float x) {
    // (1-ALPHA)=0.75, t=0 term: 0.75 * p^2 * (max(x,0)+log1p(exp(-|x|)))
    float ax = fabsf(x);
    float e  = __expf(-ax);
    float s  = 1.f + e;
    float r  = __builtin_amdgcn_rcpf(s);
    float l1p = __logf(s);
    float ce0 = fmaxf(x, 0.f) + l1p;
    float pr  = (x >= 0.f) ? r : e * r;      // sigmoid(x)
    return 0.75f * pr * pr * ce0;
}

__device__ __forceinline__ float focal_target_corr(float x) {
    // replace t=0 term with t=1 term for the target class
    float ax = fabsf(x);
    float e  = __expf(-ax);
    float s  = 1.f + e;
    float r  = __builtin_amdgcn_rcpf(s);
    float l1p = __logf(s);
    float ce0 = fmaxf(x, 0.f) + l1p;
    float pr  = (x >= 0.f) ? r : e * r;
    float om  = 1.f - pr;
    return 0.25f * om * om * (ce0 - x) - 0.75f * pr * pr * ce0;
}

__global__ __launch_bounds__(256) void yolo_fused_kernel(
    const float* __restrict__ box_preds,   // [B,N,4]
    const float* __restrict__ cls_preds,   // [B,N,C]
    const float* __restrict__ gt_boxes,    // [B,M,4]
    const int*   __restrict__ gt_labels,   // [B,M]
    double* __restrict__ acc,              // {box_l, cls_l, npos}
    int N)
{
    const int b    = blockIdx.y;
    const int tid  = threadIdx.x;
    const int half = tid >> 7;          // 0: GT[0,64), 1: GT[64,128)
    const int a    = tid & 127;         // anchor slot within block
    const int n    = blockIdx.x * QBLK + a;

    __shared__ float4   sgt[M_GT];
    __shared__ int      slbl[M_GT];
    __shared__ float    hbest[QBLK];
    __shared__ int      hidx[QBLK];
    __shared__ int      s_cnt;
    __shared__ unsigned plist[QBLK];
    __shared__ float    redb[4], redc[4];

    if (tid == 0) s_cnt = 0;
    if (tid < M_GT) {
        sgt[tid]  = reinterpret_cast<const float4*>(gt_boxes + (size_t)b * M_GT * 4)[tid];
        slbl[tid] = gt_labels[b * M_GT + tid];
    }
    __syncthreads();

    float4 p = reinterpret_cast<const float4*>(box_preds + (size_t)b * N * 4)[n];
    const float aw = p.z - p.x, ah = p.w - p.y, a1 = aw * ah;

    // wave-uniform GT base -> broadcast ds_read_b128
    const float4* gbase = &sgt[half << 6];

    float best = -1e30f;    // tracks gip = giou + 1
    int   bloc = 0;
    #pragma unroll 4
    for (int m = 0; m < 64; ++m) {
        float4 g = gbase[m];
        float gw = g.z - g.x, gh = g.w - g.y;
        float gA = gw * gh;
        float dx = fminf(p.z, g.z) - fmaxf(p.x, g.x);   // unclamped intersection extents
        float dy = fminf(p.w, g.w) - fmaxf(p.y, g.y);
        float ex = (aw + gw) - dx;                      // exact: max(r)-min(l) = w1+w2-dx
        float ey = (ah + gh) - dy;
        float inter = fmaxf(dx, 0.f) * fmaxf(dy, 0.f);
        float uni = (a1 + gA) - inter;
        float ae  = ex * ey;
        // giou + 1 = (inter*ae + uni^2) / (uni*ae)   -- single division
        float numer = fmaf(uni, uni, inter * ae);
        float gip = numer * __builtin_amdgcn_rcpf(uni * ae);
        if (gip > best) { best = gip; bloc = m; }       // strict > keeps first idx
    }
    int bidx = bloc + (half << 6);

    // merge the two GT halves (lower half has lower indices -> first-wins ties)
    if (half) { hbest[a] = best; hidx[a] = bidx; }
    __syncthreads();
    if (!half) {
        float hb = hbest[a];
        if (hb > best) { best = hb; bidx = hidx[a]; }
    }

    const int lane = tid & 63, wave = tid >> 6;
    bool  pos   = (!half) && (best > 1.3f);     // giou > 0.3
    float box_l = pos ? (2.f - best) : 0.f;     // 1 - giou

    // block-level compaction of positives into LDS (only waves 0,1 can be pos)
    {
        unsigned long long mk = __ballot(pos);
        int cw = __popcll(mk);
        if (cw > 0) {
            int leader = __ffsll(mk) - 1;
            int base = 0;
            if (lane == leader) base = atomicAdd(&s_cnt, cw);
            base = __shfl(base, leader);
            if (pos) {
                int pre = __popcll(mk & ((1ull << lane) - 1ull));
                plist[base + pre] = ((unsigned)slbl[bidx] << 18) | (unsigned)(b * N + n);
            }
        }
    }
    __syncthreads();

    // focal over the block's compacted positives (~8 avg), all 4 waves
    const int cnt = s_cnt;
    float cls_l = 0.f;
    for (int i = tid; i < cnt; i += 256) {
        unsigned u = plist[i];
        int row = (int)(u & 0x3FFFFu);
        int lbl = (int)(u >> 18);
        const float* xrow = cls_preds + (size_t)row * NUM_CLASSES;
        float cl = 0.f;
        #pragma unroll 5
        for (int c4 = 0; c4 < NUM_CLASSES / 4; ++c4) {
            float4 xv = reinterpret_cast<const float4*>(xrow)[c4];
            cl += focal_neg(xv.x);
            cl += focal_neg(xv.y);
            cl += focal_neg(xv.z);
            cl += focal_neg(xv.w);
        }
        cl += focal_target_corr(xrow[lbl]);
        cls_l += cl;
    }

    // reductions: wave shfl, then block via LDS
    #pragma unroll
    for (int off = 32; off > 0; off >>= 1) {
        box_l += __shfl_down(box_l, off);
        cls_l += __shfl_down(cls_l, off);
    }
    if (lane == 0) { redb[wave] = box_l; redc[wave] = cls_l; }
    __syncthreads();
    if (tid == 0) {
        float b0 = redb[0] + redb[1] + redb[2] + redb[3];
        float c0 = redc[0] + redc[1] + redc[2] + redc[3];
        atomicAdd(&acc[0], (double)b0);
        atomicAdd(&acc[1], (double)c0);
        atomicAdd(&acc[2], (double)cnt);
    }
}

__global__ void yolo_finalize(const double* __restrict__ acc, float* __restrict__ out) {
    if (threadIdx.x == 0) {
        double loss = (5.0 * acc[0] + acc[1]) / fmax(acc[2], 1.0);
        out[0] = (float)loss;
    }
}

extern "C" void kernel_launch(void* const* d_in, const int* in_sizes, int n_in,
                              void* d_out, int out_size, void* d_ws, size_t ws_size,
                              hipStream_t stream) {
    const float* box_preds = (const float*)d_in[0];
    const float* cls_preds = (const float*)d_in[1];
    const float* gt_boxes  = (const float*)d_in[2];
    const int*   gt_labels = (const int*)d_in[3];

    const int B = in_sizes[3] / M_GT;            // gt_labels is [B,M]
    const int N = in_sizes[0] / (4 * B);         // box_preds is [B,N,4]

    double* acc = (double*)d_ws;
    float*  out = (float*)d_out;

    yolo_init_acc<<<1, 64, 0, stream>>>(acc);

    dim3 grid((N + QBLK - 1) / QBLK, B);
    yolo_fused_kernel<<<grid, 256, 0, stream>>>(box_preds, cls_preds, gt_boxes,
                                                gt_labels, acc, N);

    yolo_finalize<<<1, 64, 0, stream>>>(acc, out);
}

// Round 7
// 94.179 us; speedup vs baseline: 1.0360x; 1.0360x over previous
//
#include <hip/hip_runtime.h>
#include <math.h>

#define NUM_CLASSES 80
#define M_GT 128
#define NBX 16
#define NBY 16
#define NBK (NBX * NBY)

// ws layout: [0,32)   double acc[3] = {box_l, cls_l, npos}
//            [32, 32+B*NBK*4)  int hist/cursors (B=16 -> 16 KB)
//            [32768, 32768+B*N*2)  ushort perm (512 KB)

__device__ __forceinline__ int bucket_of(float x, float y) {
    int bx = (int)(x * (1.f / 32.f)); bx = bx < 0 ? 0 : (bx > NBX - 1 ? NBX - 1 : bx);
    int by = (int)(y * (1.f / 32.f)); by = by < 0 ? 0 : (by > NBY - 1 ? NBY - 1 : by);
    return by * NBX + bx;
}

__global__ void yolo_init(double* acc, int* hist, int nh) {
    int t = blockIdx.x * blockDim.x + threadIdx.x;
    if (t < 3) acc[t] = 0.0;
    for (int i = t; i < nh; i += gridDim.x * blockDim.x) hist[i] = 0;
}

__global__ __launch_bounds__(256) void yolo_bucket_hist(
    const float* __restrict__ box_preds, int* __restrict__ hist, int N)
{
    const int b = blockIdx.y;
    const int i = blockIdx.x * 256 + threadIdx.x;
    if (i < N) {
        const float* p = box_preds + ((size_t)b * N + i) * 4;
        atomicAdd(&hist[b * NBK + bucket_of(p[0], p[1])], 1);
    }
}

__global__ __launch_bounds__(256) void yolo_bucket_scan(int* __restrict__ hist) {
    const int b = blockIdx.x;
    const int t = threadIdx.x;
    __shared__ int s[NBK];
    int v = hist[b * NBK + t];
    s[t] = v; __syncthreads();
    for (int d = 1; d < NBK; d <<= 1) {
        int x = (t >= d) ? s[t - d] : 0;
        __syncthreads();
        s[t] += x;
        __syncthreads();
    }
    hist[b * NBK + t] = s[t] - v;   // exclusive prefix
}

__global__ __launch_bounds__(256) void yolo_bucket_scatter(
    const float* __restrict__ box_preds, int* __restrict__ hist,
    unsigned short* __restrict__ perm, int N)
{
    const int b = blockIdx.y;
    const int i = blockIdx.x * 256 + threadIdx.x;
    if (i < N) {
        const float* p = box_preds + ((size_t)b * N + i) * 4;
        int slot = atomicAdd(&hist[b * NBK + bucket_of(p[0], p[1])], 1);
        perm[(size_t)b * N + slot] = (unsigned short)i;
    }
}

__device__ __forceinline__ float focal_neg(float x) {
    float ax = fabsf(x);
    float e  = __expf(-ax);
    float s  = 1.f + e;
    float r  = __builtin_amdgcn_rcpf(s);
    float l1p = __logf(s);
    float ce0 = fmaxf(x, 0.f) + l1p;
    float pr  = (x >= 0.f) ? r : e * r;      // sigmoid(x)
    return 0.75f * pr * pr * ce0;
}

__device__ __forceinline__ float focal_target_corr(float x) {
    float ax = fabsf(x);
    float e  = __expf(-ax);
    float s  = 1.f + e;
    float r  = __builtin_amdgcn_rcpf(s);
    float l1p = __logf(s);
    float ce0 = fmaxf(x, 0.f) + l1p;
    float pr  = (x >= 0.f) ? r : e * r;
    float om  = 1.f - pr;
    return 0.25f * om * om * (ce0 - x) - 0.75f * pr * pr * ce0;
}

__global__ __launch_bounds__(256) void yolo_main_kernel(
    const float* __restrict__ box_preds,   // [B,N,4]
    const float* __restrict__ cls_preds,   // [B,N,C]
    const float* __restrict__ gt_boxes,    // [B,M,4]
    const int*   __restrict__ gt_labels,   // [B,M]
    const unsigned short* __restrict__ perm,
    double* __restrict__ acc, int N)
{
    const int b    = blockIdx.y;
    const int tid  = threadIdx.x;
    const int lane = tid & 63;
    const int wave = tid >> 6;

    __shared__ float4   cbox[M_GT];
    __shared__ int      cmeta[M_GT];
    __shared__ float4   sbb[4];
    __shared__ int      s_nc, s_cnt;
    __shared__ unsigned plist[256];
    __shared__ float    redb[4], redc[4];

    if (tid == 0) { s_cnt = 0; }

    // gather this block's (spatially coherent) anchors
    const int n = (int)perm[(size_t)b * N + blockIdx.x * 256 + tid];
    float4 p = reinterpret_cast<const float4*>(box_preds + (size_t)b * N * 4)[n];
    const float aw = p.z - p.x, ah = p.w - p.y, a1 = aw * ah;

    // block bbox: wave shfl-reduce then cross-wave via LDS
    float bx1 = p.x, by1 = p.y, bx2 = p.z, by2 = p.w;
    #pragma unroll
    for (int off = 32; off > 0; off >>= 1) {
        bx1 = fminf(bx1, __shfl_down(bx1, off));
        by1 = fminf(by1, __shfl_down(by1, off));
        bx2 = fmaxf(bx2, __shfl_down(bx2, off));
        by2 = fmaxf(by2, __shfl_down(by2, off));
    }
    if (lane == 0) sbb[wave] = make_float4(bx1, by1, bx2, by2);
    __syncthreads();
    float4 q0 = sbb[0], q1 = sbb[1], q2 = sbb[2], q3 = sbb[3];
    const float BX1 = fminf(fminf(q0.x, q1.x), fminf(q2.x, q3.x));
    const float BY1 = fminf(fminf(q0.y, q1.y), fminf(q2.y, q3.y));
    const float BX2 = fmaxf(fmaxf(q0.z, q1.z), fmaxf(q2.z, q3.z));
    const float BY2 = fmaxf(fmaxf(q0.w, q1.w), fmaxf(q2.w, q3.w));

    // exact GT filter vs block bbox — order-preserving compaction by wave 0
    if (wave == 0) {
        const float4* gt = reinterpret_cast<const float4*>(gt_boxes + (size_t)b * M_GT * 4);
        // GTs [0,64)
        float4 g0 = gt[lane];
        bool k0 = (g0.x <= BX2) && (g0.z >= BX1) && (g0.y <= BY2) && (g0.w >= BY1);
        unsigned long long mk0 = __ballot(k0);
        int cnt0 = __popcll(mk0);
        if (k0) {
            int slot = __popcll(mk0 & ((1ull << lane) - 1ull));
            cbox[slot]  = g0;
            cmeta[slot] = (gt_labels[b * M_GT + lane] << 7) | lane;
        }
        // GTs [64,128)
        float4 g1 = gt[lane + 64];
        bool k1 = (g1.x <= BX2) && (g1.z >= BX1) && (g1.y <= BY2) && (g1.w >= BY1);
        unsigned long long mk1 = __ballot(k1);
        if (k1) {
            int slot = cnt0 + __popcll(mk1 & ((1ull << lane) - 1ull));
            cbox[slot]  = g1;
            cmeta[slot] = (gt_labels[b * M_GT + lane + 64] << 7) | (lane + 64);
        }
        if (lane == 0) s_nc = cnt0 + __popcll(mk1);
    }
    __syncthreads();

    // scan candidates (block-uniform trip count, broadcast LDS reads)
    const int nc = s_nc;
    float best = -1e30f;    // tracks gip = giou + 1
    int   bslot = 0;
    #pragma unroll 2
    for (int i = 0; i < nc; ++i) {
        float4 g = cbox[i];
        float gw = g.z - g.x, gh = g.w - g.y;
        float gA = gw * gh;
        float dx = fminf(p.z, g.z) - fmaxf(p.x, g.x);
        float dy = fminf(p.w, g.w) - fmaxf(p.y, g.y);
        float ex = (aw + gw) - dx;                  // enclosure extents (identity)
        float ey = (ah + gh) - dy;
        float inter = fmaxf(dx, 0.f) * fmaxf(dy, 0.f);
        float uni = (a1 + gA) - inter;
        float ae  = ex * ey;
        // giou + 1 = (inter*ae + uni^2) / (uni*ae) — single reciprocal
        float numer = fmaf(uni, uni, inter * ae);
        float gip = numer * __builtin_amdgcn_rcpf(uni * ae);
        if (gip > best) { best = gip; bslot = i; }  // strict > keeps first (orig order kept)
    }

    bool  pos   = (best > 1.3f);                    // giou > 0.3
    float box_l = pos ? (2.f - best) : 0.f;         // 1 - giou

    // block-level compaction of positives
    {
        unsigned long long mk = __ballot(pos);
        int cw = __popcll(mk);
        if (cw > 0) {
            int leader = __ffsll(mk) - 1;
            int base = 0;
            if (lane == leader) base = atomicAdd(&s_cnt, cw);
            base = __shfl(base, leader);
            if (pos) {
                int pre = __popcll(mk & ((1ull << lane) - 1ull));
                unsigned lbl = (unsigned)(cmeta[bslot] >> 7);
                plist[base + pre] = (lbl << 18) | (unsigned)(b * N + n);
            }
        }
    }
    __syncthreads();

    // focal over compacted positives
    const int cnt = s_cnt;
    float cls_l = 0.f;
    for (int i = tid; i < cnt; i += 256) {
        unsigned u = plist[i];
        int row = (int)(u & 0x3FFFFu);
        int lbl = (int)(u >> 18);
        const float* xrow = cls_preds + (size_t)row * NUM_CLASSES;
        float cl = 0.f;
        #pragma unroll 5
        for (int c4 = 0; c4 < NUM_CLASSES / 4; ++c4) {
            float4 xv = reinterpret_cast<const float4*>(xrow)[c4];
            cl += focal_neg(xv.x);
            cl += focal_neg(xv.y);
            cl += focal_neg(xv.z);
            cl += focal_neg(xv.w);
        }
        cl += focal_target_corr(xrow[lbl]);
        cls_l += cl;
    }

    // reductions
    #pragma unroll
    for (int off = 32; off > 0; off >>= 1) {
        box_l += __shfl_down(box_l, off);
        cls_l += __shfl_down(cls_l, off);
    }
    if (lane == 0) { redb[wave] = box_l; redc[wave] = cls_l; }
    __syncthreads();
    if (tid == 0) {
        float b0 = redb[0] + redb[1] + redb[2] + redb[3];
        float c0 = redc[0] + redc[1] + redc[2] + redc[3];
        atomicAdd(&acc[0], (double)b0);
        atomicAdd(&acc[1], (double)c0);
        atomicAdd(&acc[2], (double)cnt);
    }
}

__global__ void yolo_finalize(const double* __restrict__ acc, float* __restrict__ out) {
    if (threadIdx.x == 0) {
        double loss = (5.0 * acc[0] + acc[1]) / fmax(acc[2], 1.0);
        out[0] = (float)loss;
    }
}

extern "C" void kernel_launch(void* const* d_in, const int* in_sizes, int n_in,
                              void* d_out, int out_size, void* d_ws, size_t ws_size,
                              hipStream_t stream) {
    const float* box_preds = (const float*)d_in[0];
    const float* cls_preds = (const float*)d_in[1];
    const float* gt_boxes  = (const float*)d_in[2];
    const int*   gt_labels = (const int*)d_in[3];

    const int B = in_sizes[3] / M_GT;            // gt_labels is [B,M]
    const int N = in_sizes[0] / (4 * B);         // box_preds is [B,N,4]

    double*         acc  = (double*)d_ws;
    int*            hist = (int*)((char*)d_ws + 32);
    unsigned short* perm = (unsigned short*)((char*)d_ws + 32768);
    float*          out  = (float*)d_out;

    yolo_init<<<16, 256, 0, stream>>>(acc, hist, B * NBK);

    dim3 gridN((N + 255) / 256, B);
    yolo_bucket_hist<<<gridN, 256, 0, stream>>>(box_preds, hist, N);
    yolo_bucket_scan<<<B, NBK, 0, stream>>>(hist);
    yolo_bucket_scatter<<<gridN, 256, 0, stream>>>(box_preds, hist, perm, N);

    yolo_main_kernel<<<gridN, 256, 0, stream>>>(box_preds, cls_preds, gt_boxes,
                                                gt_labels, perm, acc, N);

    yolo_finalize<<<1, 64, 0, stream>>>(acc, out);
}

// Round 8
// 37.130 us; speedup vs baseline: 2.6278x; 2.5365x over previous
//
#include <hip/hip_runtime.h>
#include <math.h>

#define NUM_CLASSES 80
#define M_GT 128

__device__ __forceinline__ float focal_neg(float x) {
    // (1-ALPHA)=0.75, t=0 term: 0.75 * p^2 * (max(x,0)+log1p(exp(-|x|)))
    float ax = fabsf(x);
    float e  = __expf(-ax);
    float s  = 1.f + e;
    float r  = __builtin_amdgcn_rcpf(s);
    float l1p = __logf(s);
    float ce0 = fmaxf(x, 0.f) + l1p;
    float pr  = (x >= 0.f) ? r : e * r;      // sigmoid(x)
    return 0.75f * pr * pr * ce0;
}

__device__ __forceinline__ float focal_target_corr(float x) {
    // replace t=0 term with t=1 term for the target class
    float ax = fabsf(x);
    float e  = __expf(-ax);
    float s  = 1.f + e;
    float r  = __builtin_amdgcn_rcpf(s);
    float l1p = __logf(s);
    float ce0 = fmaxf(x, 0.f) + l1p;
    float pr  = (x >= 0.f) ? r : e * r;
    float om  = 1.f - pr;
    return 0.25f * om * om * (ce0 - x) - 0.75f * pr * pr * ce0;
}

__global__ __launch_bounds__(256) void yolo_fused_kernel(
    const float* __restrict__ box_preds,   // [B,N,4]
    const float* __restrict__ cls_preds,   // [B,N,C]
    const float* __restrict__ gt_boxes,    // [B,M,4]
    const int*   __restrict__ gt_labels,   // [B,M]
    float4* __restrict__ partials,         // [gridDim.y*gridDim.x] per-block {box,cls,npos}
    int N)
{
    const int b    = blockIdx.y;
    const int tid  = threadIdx.x;
    const int n    = blockIdx.x * 256 + tid;
    const int lane = tid & 63;
    const int wave = tid >> 6;

    __shared__ float4   sgt[M_GT];
    __shared__ int      slbl[M_GT];
    __shared__ int      s_cnt;
    __shared__ unsigned plist[256];
    __shared__ float    redb[4], redc[4];

    if (tid == 0) s_cnt = 0;
    if (tid < M_GT) {
        sgt[tid]  = reinterpret_cast<const float4*>(gt_boxes + (size_t)b * M_GT * 4)[tid];
        slbl[tid] = gt_labels[b * M_GT + tid];
    }
    __syncthreads();

    const int nld = (n < N) ? n : (N - 1);
    float4 p = reinterpret_cast<const float4*>(box_preds + (size_t)b * N * 4)[nld];
    const float aw = p.z - p.x, ah = p.w - p.y, a1 = aw * ah;

    // ---- pass 1: cheap overlap masks (inter>0 is necessary for giou>0.3) ----
    unsigned mk[4];
    #pragma unroll
    for (int q = 0; q < 4; ++q) {
        unsigned mm = 0;
        #pragma unroll 8
        for (int t = 0; t < 32; ++t) {
            float4 g = sgt[q * 32 + t];
            float dx = fminf(p.z, g.z) - fmaxf(p.x, g.x);
            float dy = fminf(p.w, g.w) - fmaxf(p.y, g.y);
            mm |= (fminf(dx, dy) > 0.f) ? (1u << t) : 0u;
        }
        mk[q] = mm;
    }

    // ---- pass 2: full GIoU only on overlapping GTs (ascending order -> first-max kept) ----
    float best = -1e30f;   // tracks gip = giou + 1
    int   bidx = 0;
    #pragma unroll
    for (int q = 0; q < 4; ++q) {
        unsigned mm = mk[q];
        while (mm) {
            int t = __ffs(mm) - 1;
            mm &= mm - 1;
            int m = q * 32 + t;
            float4 g = sgt[m];                    // per-lane (divergent) LDS read, few iters
            float gw = g.z - g.x, gh = g.w - g.y, gA = gw * gh;
            float dx = fminf(p.z, g.z) - fmaxf(p.x, g.x);   // >0 guaranteed by mask
            float dy = fminf(p.w, g.w) - fmaxf(p.y, g.y);   // >0 guaranteed by mask
            float ex = (aw + gw) - dx;            // enclosure extents (identity)
            float ey = (ah + gh) - dy;
            float inter = dx * dy;                // no clamp needed: dx,dy > 0
            float uni = (a1 + gA) - inter;
            float ae  = ex * ey;
            // giou + 1 = (inter*ae + uni^2) / (uni*ae) — single reciprocal
            float gip = fmaf(uni, uni, inter * ae) * __builtin_amdgcn_rcpf(uni * ae);
            if (gip > best) { best = gip; bidx = m; }   // strict > keeps first idx
        }
    }
    // Exactness: any positive anchor (giou>0.3) has inter>0 with its argmax GT, and all
    // non-overlapping GTs have giou<0, so subset-argmax == global argmax for positives.
    // Negative anchors contribute nothing regardless of their argmax.

    bool  pos   = (n < N) && (best > 1.3f);     // giou > 0.3
    float box_l = pos ? (2.f - best) : 0.f;     // 1 - giou  (elementwise giou == best)

    // ---- block-level compaction of positives ----
    {
        unsigned long long mkb = __ballot(pos);
        int cw = __popcll(mkb);
        if (cw > 0) {
            int leader = __ffsll(mkb) - 1;
            int base = 0;
            if (lane == leader) base = atomicAdd(&s_cnt, cw);   // LDS atomic, per-block
            base = __shfl(base, leader);
            if (pos) {
                int pre = __popcll(mkb & ((1ull << lane) - 1ull));
                plist[base + pre] = ((unsigned)slbl[bidx] << 18) | (unsigned)(b * N + n);
            }
        }
    }
    __syncthreads();

    // ---- focal over compacted positives (~17/block avg) ----
    const int cnt = s_cnt;
    float cls_l = 0.f;
    for (int i = tid; i < cnt; i += 256) {
        unsigned u = plist[i];
        int row = (int)(u & 0x3FFFFu);
        int lbl = (int)(u >> 18);
        const float* xrow = cls_preds + (size_t)row * NUM_CLASSES;
        float cl = 0.f;
        #pragma unroll 5
        for (int c4 = 0; c4 < NUM_CLASSES / 4; ++c4) {
            float4 xv = reinterpret_cast<const float4*>(xrow)[c4];
            cl += focal_neg(xv.x);
            cl += focal_neg(xv.y);
            cl += focal_neg(xv.z);
            cl += focal_neg(xv.w);
        }
        cl += focal_target_corr(xrow[lbl]);
        cls_l += cl;
    }

    // ---- block reduction, then ONE plain store per block (no global atomics) ----
    #pragma unroll
    for (int off = 32; off > 0; off >>= 1) {
        box_l += __shfl_down(box_l, off);
        cls_l += __shfl_down(cls_l, off);
    }
    if (lane == 0) { redb[wave] = box_l; redc[wave] = cls_l; }
    __syncthreads();
    if (tid == 0) {
        float b0 = redb[0] + redb[1] + redb[2] + redb[3];
        float c0 = redc[0] + redc[1] + redc[2] + redc[3];
        partials[blockIdx.y * gridDim.x + blockIdx.x] = make_float4(b0, c0, (float)cnt, 0.f);
    }
}

__global__ __launch_bounds__(256) void yolo_reduce(const float4* __restrict__ partials,
                                                   int nb, float* __restrict__ out) {
    const int tid = threadIdx.x;
    const int lane = tid & 63, wave = tid >> 6;
    double sb = 0.0, sc = 0.0, sp = 0.0;
    for (int i = tid; i < nb; i += 256) {
        float4 v = partials[i];
        sb += (double)v.x; sc += (double)v.y; sp += (double)v.z;
    }
    #pragma unroll
    for (int off = 32; off > 0; off >>= 1) {
        sb += __shfl_down(sb, off);
        sc += __shfl_down(sc, off);
        sp += __shfl_down(sp, off);
    }
    __shared__ double rb[4], rc[4], rp[4];
    if (lane == 0) { rb[wave] = sb; rc[wave] = sc; rp[wave] = sp; }
    __syncthreads();
    if (tid == 0) {
        double B0 = rb[0] + rb[1] + rb[2] + rb[3];
        double C0 = rc[0] + rc[1] + rc[2] + rc[3];
        double P0 = rp[0] + rp[1] + rp[2] + rp[3];
        out[0] = (float)((5.0 * B0 + C0) / fmax(P0, 1.0));
    }
}

extern "C" void kernel_launch(void* const* d_in, const int* in_sizes, int n_in,
                              void* d_out, int out_size, void* d_ws, size_t ws_size,
                              hipStream_t stream) {
    const float* box_preds = (const float*)d_in[0];
    const float* cls_preds = (const float*)d_in[1];
    const float* gt_boxes  = (const float*)d_in[2];
    const int*   gt_labels = (const int*)d_in[3];

    const int B = in_sizes[3] / M_GT;            // gt_labels is [B,M]
    const int N = in_sizes[0] / (4 * B);         // box_preds is [B,N,4]

    float4* partials = (float4*)d_ws;
    float*  out      = (float*)d_out;

    const int gx = (N + 255) / 256;
    dim3 grid(gx, B);
    yolo_fused_kernel<<<grid, 256, 0, stream>>>(box_preds, cls_preds, gt_boxes,
                                                gt_labels, partials, N);

    yolo_reduce<<<1, 256, 0, stream>>>(partials, gx * B, out);
}